// Round 2
// baseline (851.667 us; speedup 1.0000x reference)
//
#include <hip/hip_runtime.h>
#include <math.h>

#define NROWS 32768
#define NK    4096
#define NE    64
#define BK    32     // K-chunk staged per iteration (per quarter)
#define PITCH 68     // LDS row pitch in floats (64 + 4 pad, keeps 16B alignment, 2-way banks = free)
#define QK    1024   // K range per wave (4096 / 4 waves)

// ---------------------------------------------------------------------------
// Kernel 1: logits[t,e] = A[t,:] . W[e,:]
// grid = 512 blocks x 256 threads. Block b owns rows b*64..b*64+63, all 64 experts.
// Wave w (0..3) accumulates K range [w*1024, (w+1)*1024); cross-wave reduce in LDS.
// Thread tile: 8 rows x 8 experts. lane: col = lane&7 (experts col*8..+7),
// rowgrp = lane>>3 (rows rowgrp*8..+7). 8 consecutive lanes share A addresses
// (hardware broadcast), so A streams global->reg with exact HBM traffic.
// ---------------------------------------------------------------------------
__global__ __launch_bounds__(256, 2) void router_gemm(
    const float* __restrict__ A,   // [32768][4096]
    const float* __restrict__ W,   // [64][4096]
    float* __restrict__ L)         // [32768][64]
{
  __shared__ __align__(16) float bt[4 * BK * PITCH];  // BT[q][k][e], 34816 B

  const int tid    = threadIdx.x;
  const int wave   = tid >> 6;
  const int lane   = tid & 63;
  const int col    = lane & 7;
  const int rowgrp = lane >> 3;
  const int rb     = blockIdx.x * 64;
  const int kq     = wave * QK;

  float acc[8][8];
#pragma unroll
  for (int i = 0; i < 8; ++i)
#pragma unroll
    for (int j = 0; j < 8; ++j) acc[i][j] = 0.f;

  const float* aBase0 = A + (size_t)(rb + rowgrp * 8) * NK + kq;

  for (int t = 0; t < QK / BK; ++t) {
    // ---- stage B^T chunk (BK ks for each of the 4 K-quarters) ----
    // flat unit v = p*4 + wave in 0..31 -> quarter qs = v>>3, kk = (v&7)*4, e = lane
#pragma unroll
    for (int p = 0; p < 8; ++p) {
      const int v  = p * 4 + wave;
      const int qs = v >> 3;
      const int kk = (v & 7) * 4;
      const float4 g = *(const float4*)(W + (size_t)lane * NK + qs * QK + t * BK + kk);
      float* dst = bt + qs * (BK * PITCH) + kk * PITCH + lane;
      dst[0 * PITCH] = g.x;
      dst[1 * PITCH] = g.y;
      dst[2 * PITCH] = g.z;
      dst[3 * PITCH] = g.w;
    }
    __syncthreads();

    const float* aBase = aBase0 + t * BK;
    const float* bq    = bt + wave * (BK * PITCH);
#pragma unroll
    for (int kk = 0; kk < BK; kk += 4) {
      float4 a4[8];
#pragma unroll
      for (int i = 0; i < 8; ++i)
        a4[i] = *(const float4*)(aBase + (size_t)i * NK + kk);
#pragma unroll
      for (int d = 0; d < 4; ++d) {
        const float4 b0 = *(const float4*)(bq + (kk + d) * PITCH + col * 8);
        const float4 b1 = *(const float4*)(bq + (kk + d) * PITCH + col * 8 + 4);
        const float bb[8] = {b0.x, b0.y, b0.z, b0.w, b1.x, b1.y, b1.z, b1.w};
#pragma unroll
        for (int i = 0; i < 8; ++i) {
          const float av = (d == 0) ? a4[i].x : (d == 1) ? a4[i].y
                          : (d == 2) ? a4[i].z : a4[i].w;
#pragma unroll
          for (int j = 0; j < 8; ++j) acc[i][j] = fmaf(av, bb[j], acc[i][j]);
        }
      }
    }
    __syncthreads();
  }

  // ---- cross-wave K reduction (alias bt; need 2*64*64 = 8192 floats <= 8704) ----
  float* red = bt;
  if (wave >= 2) {
    float* r = red + (wave - 2) * 4096;
#pragma unroll
    for (int i = 0; i < 8; ++i)
#pragma unroll
      for (int j0 = 0; j0 < 8; j0 += 4)
        *(float4*)(r + (rowgrp * 8 + i) * 64 + col * 8 + j0) =
            make_float4(acc[i][j0], acc[i][j0 + 1], acc[i][j0 + 2], acc[i][j0 + 3]);
  }
  __syncthreads();
  if (wave < 2) {
    const float* r = red + wave * 4096;
#pragma unroll
    for (int i = 0; i < 8; ++i)
#pragma unroll
      for (int j0 = 0; j0 < 8; j0 += 4) {
        const float4 b = *(const float4*)(r + (rowgrp * 8 + i) * 64 + col * 8 + j0);
        acc[i][j0 + 0] += b.x;
        acc[i][j0 + 1] += b.y;
        acc[i][j0 + 2] += b.z;
        acc[i][j0 + 3] += b.w;
      }
  }
  __syncthreads();
  if (wave == 1) {
    float* r = red;
#pragma unroll
    for (int i = 0; i < 8; ++i)
#pragma unroll
      for (int j0 = 0; j0 < 8; j0 += 4)
        *(float4*)(r + (rowgrp * 8 + i) * 64 + col * 8 + j0) =
            make_float4(acc[i][j0], acc[i][j0 + 1], acc[i][j0 + 2], acc[i][j0 + 3]);
  }
  __syncthreads();
  if (wave == 0) {
    const float* r = red;
#pragma unroll
    for (int i = 0; i < 8; ++i) {
      const int row = rb + rowgrp * 8 + i;
#pragma unroll
      for (int j0 = 0; j0 < 8; j0 += 4) {
        const float4 b = *(const float4*)(r + (rowgrp * 8 + i) * 64 + col * 8 + j0);
        float4 o;
        o.x = acc[i][j0 + 0] + b.x;
        o.y = acc[i][j0 + 1] + b.y;
        o.z = acc[i][j0 + 2] + b.z;
        o.w = acc[i][j0 + 3] + b.w;
        *(float4*)(L + (size_t)row * NE + col * 8 + j0) = o;
      }
    }
  }
}

// ---------------------------------------------------------------------------
// Kernel 2: per-row top-2 of logits + renormalized softmax weights.
// Full-softmax denominator cancels: w1 = 1/(1+exp(l2-l1)), w2 = 1-w1.
// One wave per row; butterfly top-2 merge with jax tie-breaking
// (value desc, then lower index).
// ---------------------------------------------------------------------------
__global__ __launch_bounds__(256) void router_topk(
    const float* __restrict__ L,   // [32768][64]
    float* __restrict__ Wt,        // [32768][2]
    float* __restrict__ It)        // [32768][2] (indices as float)
{
  const int wave = threadIdx.x >> 6;
  const int lane = threadIdx.x & 63;
  const int row  = blockIdx.x * 4 + wave;

  float v1 = L[(size_t)row * NE + lane];
  int   i1 = lane;
  float v2 = -INFINITY;
  int   i2 = NE;

#pragma unroll
  for (int off = 32; off > 0; off >>= 1) {
    const float ov1 = __shfl_xor(v1, off);
    const int   oi1 = __shfl_xor(i1, off);
    const float ov2 = __shfl_xor(v2, off);
    const int   oi2 = __shfl_xor(i2, off);
    // merge sorted pairs (v1,i1,v2,i2) x (ov1,oi1,ov2,oi2)
    const bool obet = (ov1 > v1) || (ov1 == v1 && oi1 < i1);
    float nv1, nv2;
    int ni1, ni2;
    if (obet) {
      nv1 = ov1; ni1 = oi1;
      const bool sec = (v1 > ov2) || (v1 == ov2 && i1 < oi2);
      nv2 = sec ? v1 : ov2;
      ni2 = sec ? i1 : oi2;
    } else {
      nv1 = v1; ni1 = i1;
      const bool sec = (ov1 > v2) || (ov1 == v2 && oi1 < i2);
      nv2 = sec ? ov1 : v2;
      ni2 = sec ? oi1 : i2;
    }
    v1 = nv1; i1 = ni1; v2 = nv2; i2 = ni2;
  }

  if (lane == 0) {
    const float e  = expf(v2 - v1);       // <= 1
    const float w1 = 1.f / (1.f + e);
    const float w2 = e / (1.f + e);
    Wt[row * 2 + 0] = w1;
    Wt[row * 2 + 1] = w2;
    It[row * 2 + 0] = (float)i1;
    It[row * 2 + 1] = (float)i2;
  }
}

// ---------------------------------------------------------------------------
extern "C" void kernel_launch(void* const* d_in, const int* in_sizes, int n_in,
                              void* d_out, int out_size, void* d_ws, size_t ws_size,
                              hipStream_t stream) {
  const float* hs = (const float*)d_in[0];   // [32768][4096]
  const float* gw = (const float*)d_in[1];   // [64][4096]
  float* out = (float*)d_out;
  float* Wt = out;                           // 32768*2
  float* It = out + NROWS * 2;               // 32768*2
  float* L  = out + NROWS * 4;               // 32768*64

  router_gemm<<<NROWS / 64, 256, 0, stream>>>(hs, gw, L);
  router_topk<<<NROWS / 4, 256, 0, stream>>>(L, Wt, It);
}

// Round 5
// 817.047 us; speedup vs baseline: 1.0424x; 1.0424x over previous
//
#include <hip/hip_runtime.h>
#include <math.h>

#define NROWS 32768
#define NK    4096
#define NE    64
#define NSTEP 128   // K steps of 32

typedef __attribute__((ext_vector_type(8))) short bf16x8;
typedef __attribute__((ext_vector_type(4))) float f32x4;

static __device__ __forceinline__ unsigned short f2bf(float f) {
  unsigned u = __float_as_uint(f);
  u += 0x7FFFu + ((u >> 16) & 1u);   // RNE
  return (unsigned short)(u >> 16);
}
static __device__ __forceinline__ float bf2f(unsigned short h) {
  return __uint_as_float(((unsigned)h) << 16);
}
// fp32 -> hi+mid+lo bf16 (residual <= 2^-27 relative: fp32-equivalent GEMM)
static __device__ __forceinline__ void split3(float w, unsigned short& h,
                                              unsigned short& m, unsigned short& l) {
  h = f2bf(w); const float r1 = w - bf2f(h);
  m = f2bf(r1); const float r2 = r1 - bf2f(m);
  l = f2bf(r2);
}

// ---------------------------------------------------------------------------
// Prep: repack gate_w fp32 [64][4096] into MFMA B-fragment layout, split-3.
// Unit u (16B): lane = u&63, f = u>>6; h = f%3, n = (f/3)&3, s = f/12.
// Content: W_h[e = n*16 + (lane&15)][k = s*32 + (lane>>4)*8 + j], j=0..7.
// 98304 units = 1.5 MB in d_ws.
// ---------------------------------------------------------------------------
__global__ __launch_bounds__(256) void prep_w(const float* __restrict__ W,
                                              unsigned short* __restrict__ Wp) {
  const int u    = blockIdx.x * 256 + threadIdx.x;   // 0..98303
  const int lane = u & 63;
  const int f    = u >> 6;                           // 0..1535
  const int h    = f % 3;
  const int g    = f / 3;
  const int n    = g & 3;
  const int s    = g >> 2;
  const int e    = n * 16 + (lane & 15);
  const int k    = s * 32 + (lane >> 4) * 8;
  const float* src = W + (size_t)e * NK + k;
  bf16x8 o;
#pragma unroll
  for (int j = 0; j < 8; ++j) {
    unsigned short hh, mm, ll;
    split3(src[j], hh, mm, ll);
    o[j] = (short)(h == 0 ? hh : (h == 1 ? mm : ll));
  }
  *(bf16x8*)(Wp + (size_t)u * 8) = o;
}

// ---------------------------------------------------------------------------
// Fused router: split-3 bf16 MFMA GEMM (fp32-accurate) + logits write +
// in-register top-2 softmax epilogue. No LDS, no barriers: pure dataflow,
// register prefetch of A one step ahead. grid 512 x 256 (2 blocks/CU).
// Wave tile: 16 rows x 64 experts. A frag: lane holds row=lane&15,
// k = s*32 + (lane>>4)*8 .. +7 (8 contiguous fp32 -> split to 3 bf16x8).
// C frag: col(expert-in-tile)=lane&15, row=(lane>>4)*4+reg  [m89].
// Little's law: 2 dwordx4/wave in flight = 2 KB/wave x 8 waves/CU = 16 KB
// outstanding > 9.2 KB needed for 10.25 B/cyc/CU at ~900 cyc latency.
// ---------------------------------------------------------------------------
template<bool PACKED>
__global__ __launch_bounds__(256, 2) void router_mfma(
    const float* __restrict__ A, const float* __restrict__ W,
    const unsigned short* __restrict__ Wp,
    float* __restrict__ Wt, float* __restrict__ It, float* __restrict__ L)
{
  const int lane = threadIdx.x & 63;
  const int wave = threadIdx.x >> 6;
  const int col  = lane & 15;
  const int kg   = lane >> 4;
  const int rb   = blockIdx.x * 64 + wave * 16;

  f32x4 acc[4];
#pragma unroll
  for (int n = 0; n < 4; ++n) acc[n] = (f32x4){0.f, 0.f, 0.f, 0.f};

  const float* ap = A + (size_t)(rb + col) * NK + kg * 8;
  f32x4 a0 = __builtin_nontemporal_load((const f32x4*)ap);
  f32x4 a1 = __builtin_nontemporal_load((const f32x4*)(ap + 4));

  for (int s = 0; s < NSTEP; ++s) {
    const int sn = (s < NSTEP - 1) ? s + 1 : s;
    f32x4 p0 = __builtin_nontemporal_load((const f32x4*)(ap + (size_t)sn * 32));
    f32x4 p1 = __builtin_nontemporal_load((const f32x4*)(ap + (size_t)sn * 32 + 4));

    // split current A 8 elems -> 3 bf16x8 fragments
    bf16x8 ah, am, al;
#pragma unroll
    for (int j = 0; j < 4; ++j) {
      unsigned short hh, mm, ll;
      split3(a0[j], hh, mm, ll);
      ah[j] = (short)hh; am[j] = (short)mm; al[j] = (short)ll;
    }
#pragma unroll
    for (int j = 0; j < 4; ++j) {
      unsigned short hh, mm, ll;
      split3(a1[j], hh, mm, ll);
      ah[4 + j] = (short)hh; am[4 + j] = (short)mm; al[4 + j] = (short)ll;
    }

    bf16x8 bh[4], bm[4], bl[4];
    if constexpr (PACKED) {
      const char* wb = (const char*)Wp + (size_t)s * 12288 + lane * 16;
#pragma unroll
      for (int n = 0; n < 4; ++n) {
        bh[n] = *(const bf16x8*)(wb + (n * 3 + 0) * 1024);
        bm[n] = *(const bf16x8*)(wb + (n * 3 + 1) * 1024);
        bl[n] = *(const bf16x8*)(wb + (n * 3 + 2) * 1024);
      }
    } else {
#pragma unroll
      for (int n = 0; n < 4; ++n) {
        const float* wsrc = W + (size_t)(n * 16 + col) * NK + s * 32 + kg * 8;
        const f32x4 w0 = *(const f32x4*)wsrc;
        const f32x4 w1 = *(const f32x4*)(wsrc + 4);
#pragma unroll
        for (int j = 0; j < 4; ++j) {
          unsigned short hh, mm, ll;
          split3(w0[j], hh, mm, ll);
          bh[n][j] = (short)hh; bm[n][j] = (short)mm; bl[n][j] = (short)ll;
        }
#pragma unroll
        for (int j = 0; j < 4; ++j) {
          unsigned short hh, mm, ll;
          split3(w1[j], hh, mm, ll);
          bh[n][4 + j] = (short)hh; bm[n][4 + j] = (short)mm; bl[n][4 + j] = (short)ll;
        }
      }
    }

    // 6 products per tile: hh + hm + mh + mm + hl + lh (dropped terms ~2^-27)
#pragma unroll
    for (int n = 0; n < 4; ++n) {
      acc[n] = __builtin_amdgcn_mfma_f32_16x16x32_bf16(ah, bh[n], acc[n], 0, 0, 0);
      acc[n] = __builtin_amdgcn_mfma_f32_16x16x32_bf16(ah, bm[n], acc[n], 0, 0, 0);
      acc[n] = __builtin_amdgcn_mfma_f32_16x16x32_bf16(am, bh[n], acc[n], 0, 0, 0);
      acc[n] = __builtin_amdgcn_mfma_f32_16x16x32_bf16(am, bm[n], acc[n], 0, 0, 0);
      acc[n] = __builtin_amdgcn_mfma_f32_16x16x32_bf16(ah, bl[n], acc[n], 0, 0, 0);
      acc[n] = __builtin_amdgcn_mfma_f32_16x16x32_bf16(al, bh[n], acc[n], 0, 0, 0);
    }

    a0 = p0; a1 = p1;
  }

  // ---- logits write ----
#pragma unroll
  for (int q = 0; q < 4; ++q) {
    const int row = rb + kg * 4 + q;
#pragma unroll
    for (int n = 0; n < 4; ++n)
      L[(size_t)row * NE + n * 16 + col] = acc[n][q];
  }

  // ---- fused top-2 softmax: rows live across 16-lane groups ----
#pragma unroll
  for (int q = 0; q < 4; ++q) {
    float v1 = acc[0][q]; int i1 = col;
    float v2 = -INFINITY; int i2 = NE;
#pragma unroll
    for (int n = 1; n < 4; ++n) {
      const float c = acc[n][q]; const int ci = n * 16 + col;
      if (c > v1)      { v2 = v1; i2 = i1; v1 = c; i1 = ci; }
      else if (c > v2) { v2 = c;  i2 = ci; }
    }
#pragma unroll
    for (int m = 1; m <= 8; m <<= 1) {   // stays within 16-lane group
      const float ov1 = __shfl_xor(v1, m);
      const int   oi1 = __shfl_xor(i1, m);
      const float ov2 = __shfl_xor(v2, m);
      const int   oi2 = __shfl_xor(i2, m);
      const bool obet = (ov1 > v1) || (ov1 == v1 && oi1 < i1);
      float nv1, nv2; int ni1, ni2;
      if (obet) {
        nv1 = ov1; ni1 = oi1;
        const bool sec = (v1 > ov2) || (v1 == ov2 && i1 < oi2);
        nv2 = sec ? v1 : ov2; ni2 = sec ? i1 : oi2;
      } else {
        nv1 = v1; ni1 = i1;
        const bool sec = (ov1 > v2) || (ov1 == v2 && oi1 < i2);
        nv2 = sec ? ov1 : v2; ni2 = sec ? oi1 : i2;
      }
      v1 = nv1; i1 = ni1; v2 = nv2; i2 = ni2;
    }
    if (col == 0) {
      const int row = rb + kg * 4 + q;
      const float e  = expf(v2 - v1);          // <= 1
      const float w1 = 1.f / (1.f + e);
      Wt[row * 2 + 0] = w1;
      Wt[row * 2 + 1] = e / (1.f + e);
      It[row * 2 + 0] = (float)i1;
      It[row * 2 + 1] = (float)i2;
    }
  }
}

// ---------------------------------------------------------------------------
extern "C" void kernel_launch(void* const* d_in, const int* in_sizes, int n_in,
                              void* d_out, int out_size, void* d_ws, size_t ws_size,
                              hipStream_t stream) {
  const float* hs = (const float*)d_in[0];   // [32768][4096]
  const float* gw = (const float*)d_in[1];   // [64][4096]
  float* out = (float*)d_out;
  float* Wt = out;                           // 32768*2 weights
  float* It = out + NROWS * 2;               // 32768*2 indices (as float)
  float* L  = out + NROWS * 4;               // 32768*64 logits

  const size_t WP_BYTES = (size_t)98304 * 16;   // 1.5 MB packed split-3 W
  if (ws_size >= WP_BYTES) {
    prep_w<<<384, 256, 0, stream>>>(gw, (unsigned short*)d_ws);
    router_mfma<true><<<NROWS / 64, 256, 0, stream>>>(
        hs, gw, (const unsigned short*)d_ws, Wt, It, L);
  } else {
    router_mfma<false><<<NROWS / 64, 256, 0, stream>>>(
        hs, gw, nullptr, Wt, It, L);
  }
}